// Round 2
// baseline (168.178 us; speedup 1.0000x reference)
//
#include <hip/hip_runtime.h>
#include <hip/hip_fp16.h>

#define N_NODES 50000
#define N_EDGES 800000
#define D_FEAT  64
#define CAP     32                      // slots/node: P(deg>32)~1e-5
#define SPILL_CAP 262144                // 2 MB; input is Poisson(16) -> ~0 used
#define FILL_BLOCKS 2048                // 8 partitions x 256 blocks
#define PULL_BLOCKS ((N_NODES / 16) * 8)  // 25000: (node,half) tasks, XCD-split
#define PART_MAGIC 687195ull            // ceil(2^32 / 6250); exact for dst < 2^16

// Native vectors for __builtin_nontemporal_* (HIP_vector_type is a class and
// is rejected by the builtin; ext_vector_type qualifies).
typedef float    fvec4 __attribute__((ext_vector_type(4)));
typedef unsigned uvec4 __attribute__((ext_vector_type(4)));

// ---------------------------------------------------------------------------
// Round 11b: latency-pipelined fill + XCD-partitioned half-feature pull.
//   fill: all dst quads issued up front; queue-convert iterations slid under
//         dst and src/w latency; deposits batched last. Serial chain 8->4
//         memory rounds per thread.
//   qh layout: [2][N_NODES][32] fp16 planes (3.2 MB each). Pull assigns
//         half 0 to XCDs 0-3, half 1 to XCDs 4-7 (blockIdx&7 round-robin),
//         so each XCD's gather working set fits its 4 MB L2.
//   pull: one wave per (node,half); lanes 0-31 = features, parity (lane>>5)
//         splits edges; 2 rows/gather-instr; wave-uniform 2-tier unroll with
//         in-register masking; nt loads for csr/cnt, nt store for out.
// ---------------------------------------------------------------------------

__device__ __forceinline__ unsigned pack_entry(unsigned s, float w) {
    return (s << 16) | (unsigned)__half_as_ushort(__float2half(w));
}
__device__ __forceinline__ float entry_w(unsigned e) {
    return __half2float(__ushort_as_half((unsigned short)(e & 0xffffu)));
}
__device__ __forceinline__ int part_of(int d) {
    return (int)(((unsigned long long)(unsigned)d * PART_MAGIC) >> 32);
}

// queue fvec4 (4 feats of node n) -> fp16 split-plane layout.
__device__ __forceinline__ void conv_store(__half* __restrict__ qh, int t,
                                           const fvec4 q) {
    ushort4 h;
    h.x = __half_as_ushort(__float2half(q.x));
    h.y = __half_as_ushort(__float2half(q.y));
    h.z = __half_as_ushort(__float2half(q.z));
    h.w = __half_as_ushort(__float2half(q.w));
    const int n = t >> 4;
    const int fb = (t & 15) << 2;        // feature base 0..60
    const int hf = fb >> 5;              // plane
    const int j  = fb & 31;              // feat within plane
    reinterpret_cast<ushort4*>(qh)[(size_t)hf * (N_NODES * 8) +
                                   (size_t)n * 8 + (j >> 2)] = h;
}

#define PMASK(d) ((((part_of((d).x) == part) ? 1 : 0)) | \
                  (((part_of((d).y) == part) ? 2 : 0)) | \
                  (((part_of((d).z) == part) ? 4 : 0)) | \
                  (((part_of((d).w) == part) ? 8 : 0)))

#define DEP1(dd, ss, ww) do {                                                 \
        const int pos = atomicAdd(&cnt[(dd)], 1);                             \
        if (pos < CAP) {                                                      \
            csr[(size_t)(dd) * CAP + pos] =                                   \
                pack_entry((unsigned)(ss), (ww));                             \
        } else {                                                              \
            const int sp = atomicAdd(spillcnt, 1);                            \
            if (sp < SPILL_CAP)                                               \
                spill[sp] = make_uint2((unsigned)(ss) | ((unsigned)(dd) << 16),\
                                       __float_as_uint(ww));                  \
        } } while (0)

#define DEP4(m, d, s, wv) do { if (m) {                                       \
        if ((m) & 1) DEP1((d).x, (s).x, (wv).x);                              \
        if ((m) & 2) DEP1((d).y, (s).y, (wv).y);                              \
        if ((m) & 4) DEP1((d).z, (s).z, (wv).z);                              \
        if ((m) & 8) DEP1((d).w, (s).w, (wv).w); } } while (0)

__global__ void __launch_bounds__(256)
fill_kernel(const int* __restrict__ src, const int* __restrict__ dst,
            const float* __restrict__ weight, const float* __restrict__ queue,
            int* __restrict__ cnt, unsigned* __restrict__ csr,
            __half* __restrict__ qh, uint2* __restrict__ spill,
            int* __restrict__ spillcnt) {
    const int part = blockIdx.x & 7;              // XCD id (round-robin dispatch)
    const int bip  = blockIdx.x >> 3;
    const int nq   = N_EDGES / 4;                 // 200000 quads
    const int tstride = (FILL_BLOCKS / 8) * 256;  // 65536 threads/partition
    const int t0 = bip * 256 + threadIdx.x;       // < 65536

    const int4*   dq = reinterpret_cast<const int4*>(dst);
    const int4*   sq = reinterpret_cast<const int4*>(src);
    const float4* wq = reinterpret_cast<const float4*>(weight);

    // ---- phase A: ALL dst quad loads issued up front (independent) ----
    // k=0..2 always in-bounds: t0+131072 <= 196607 < 200000. k=3 iff t0<3392.
    const int4 d0 = dq[t0];
    const int4 d1 = dq[t0 + tstride];
    const int4 d2 = dq[t0 + 2 * tstride];
    const bool v3 = (t0 + 3 * tstride) < nq;
    int4 d3 = make_int4(-1, -1, -1, -1);          // part_of(-1) = 687194 != part
    if (v3) d3 = dq[t0 + 3 * tstride];

    // ---- convert iter 0 (streaming) hides dst latency ----
    const int gtid = blockIdx.x * 256 + threadIdx.x;     // < 524288
    const int CT = N_NODES * D_FEAT / 4;                 // 800000
    const fvec4 qa = __builtin_nontemporal_load(
        reinterpret_cast<const fvec4*>(queue) + gtid);
    conv_store(qh, gtid, qa);

    // ---- phase B: ownership masks; batched conditional src/w loads ----
    const int m0 = PMASK(d0), m1 = PMASK(d1), m2 = PMASK(d2), m3 = PMASK(d3);
    int4 s0, s1, s2, s3; float4 w0, w1, w2, w3;
    if (m0) { s0 = sq[t0];               w0 = wq[t0]; }
    if (m1) { s1 = sq[t0 + tstride];     w1 = wq[t0 + tstride]; }
    if (m2) { s2 = sq[t0 + 2 * tstride]; w2 = wq[t0 + 2 * tstride]; }
    if (m3) { s3 = sq[t0 + 3 * tstride]; w3 = wq[t0 + 3 * tstride]; }

    // ---- convert iter 1 hides src/weight latency ----
    const int t1c = gtid + FILL_BLOCKS * 256;
    if (t1c < CT) {
        const fvec4 qb = __builtin_nontemporal_load(
            reinterpret_cast<const fvec4*>(queue) + t1c);
        conv_store(qh, t1c, qb);
    }

    // ---- phase C: batched deposits (atomics overlap across edges) ----
    DEP4(m0, d0, s0, w0);
    DEP4(m1, d1, s1, w1);
    DEP4(m2, d2, s2, w2);
    DEP4(m3, d3, s3, w3);
}

// One wave per (node, feature-half). XCDs 0-3 own plane 0, 4-7 own plane 1.
__global__ void __launch_bounds__(256)
pull_kernel(const __half* __restrict__ qh, const float* __restrict__ queue,
            const unsigned* __restrict__ csr, const int* __restrict__ cnt,
            const uint2* __restrict__ spill, const int* __restrict__ spillcnt,
            float* __restrict__ out) {
    const int b    = blockIdx.x;                  // 0..24999
    const int w    = b & 7;                       // XCD (round-robin dispatch)
    const int half = w >> 2;                      // XCD 0-3 -> 0, 4-7 -> 1
    const int node = (b >> 3) * 16 + (w & 3) * 4 + (threadIdx.x >> 6);
    if (node >= N_NODES) return;                  // exact: 3125*16 = 50000
    const int lane = threadIdx.x & 63;
    const int par  = lane >> 5;                   // edge parity
    const int fo   = (half << 5) | (lane & 31);   // feature in full row

    const unsigned* p  = csr + (size_t)node * CAP;
    const __half*   qp = qh + (size_t)half * (N_NODES * 32) + (lane & 31);
    const int c = min(__builtin_nontemporal_load(cnt + node), CAP);

    float acc = 0.0f;

    // 8 edges per block: 2 uniform uvec4 entry loads + 4 gathers (2 rows each).
    // Masked entries -> 0 -> row 0 * fp16(0) = 0 contribution.
#define GATHER8(base)                                                          \
    {                                                                          \
        const uvec4 ea = __builtin_nontemporal_load(                           \
            reinterpret_cast<const uvec4*>(p + (base)));                       \
        const uvec4 eb = __builtin_nontemporal_load(                           \
            reinterpret_cast<const uvec4*>(p + (base) + 4));                   \
        unsigned e0 = par ? ea.y : ea.x;                                       \
        unsigned e1 = par ? ea.w : ea.z;                                       \
        unsigned e2 = par ? eb.y : eb.x;                                       \
        unsigned e3 = par ? eb.w : eb.z;                                       \
        if ((base) + 0 + par >= c) e0 = 0u;                                    \
        if ((base) + 2 + par >= c) e1 = 0u;                                    \
        if ((base) + 4 + par >= c) e2 = 0u;                                    \
        if ((base) + 6 + par >= c) e3 = 0u;                                    \
        const float q0 = __half2float(qp[(size_t)(e0 >> 16) * 32]);            \
        const float q1 = __half2float(qp[(size_t)(e1 >> 16) * 32]);            \
        const float q2 = __half2float(qp[(size_t)(e2 >> 16) * 32]);            \
        const float q3 = __half2float(qp[(size_t)(e3 >> 16) * 32]);            \
        acc = fmaf(q0, entry_w(e0), acc);                                      \
        acc = fmaf(q1, entry_w(e1), acc);                                      \
        acc = fmaf(q2, entry_w(e2), acc);                                      \
        acc = fmaf(q3, entry_w(e3), acc);                                      \
    }

    if (c <= 16) {                                // wave-uniform tier branch
        GATHER8(0) GATHER8(8)
    } else {
        GATHER8(0) GATHER8(8) GATHER8(16) GATHER8(24)
    }
#undef GATHER8

    acc += __shfl_xor(acc, 32);                   // merge edge parities

    // Spill edges (normally zero); added post-reduce so no double count.
    const int nsp = min(*spillcnt, SPILL_CAP);
    for (int k = 0; k < nsp; ++k) {
        const uint2 u = spill[k];
        if ((u.x >> 16) == (unsigned)node)
            acc = fmaf(queue[(size_t)(u.x & 0xffffu) * D_FEAT + fo],
                       __uint_as_float(u.y), acc);
    }

    if (par == 0)
        __builtin_nontemporal_store(acc, out + (size_t)node * D_FEAT + fo);
}

// --- Fallback (round-1 scatter) if ws_size is ever too small ---------------
__global__ void __launch_bounds__(256)
scatter_add_kernel(const float* __restrict__ queue,
                   const float* __restrict__ weight,
                   const int* __restrict__ src,
                   const int* __restrict__ dst,
                   float* __restrict__ out) {
    long long tid = (long long)blockIdx.x * blockDim.x + threadIdx.x;
    int e = (int)(tid >> 4);
    int c = ((int)tid & 15) << 2;
    if (e >= N_EDGES) return;
    int s = src[e], d = dst[e];
    float w = weight[e];
    const float4 q = *reinterpret_cast<const float4*>(queue + (size_t)s * D_FEAT + c);
    float* o = out + (size_t)d * D_FEAT + c;
    atomicAdd(o + 0, q.x * w);
    atomicAdd(o + 1, q.y * w);
    atomicAdd(o + 2, q.z * w);
    atomicAdd(o + 3, q.w * w);
}

extern "C" void kernel_launch(void* const* d_in, const int* in_sizes, int n_in,
                              void* d_out, int out_size, void* d_ws, size_t ws_size,
                              hipStream_t stream) {
    const float* queue  = (const float*)d_in[0];
    const float* weight = (const float*)d_in[1];
    const int*   src    = (const int*)d_in[2];
    const int*   dst    = (const int*)d_in[3];
    float* out = (float*)d_out;

    // Workspace layout (16B-aligned blocks):
    //   csr:      N_NODES*CAP unsigned       (6.4 MB)
    //   qh:       [2][N_NODES][32] __half    (6.4 MB)
    //   spill:    SPILL_CAP uint2            (2 MB)
    //   cnt:      N_NODES int   \ zeroed together
    //   spillcnt: 1 int         /
    const size_t csr_bytes   = (size_t)N_NODES * CAP * sizeof(unsigned);
    const size_t qh_bytes    = (size_t)N_NODES * D_FEAT * sizeof(__half);
    const size_t spill_bytes = (size_t)SPILL_CAP * sizeof(uint2);
    const size_t need = csr_bytes + qh_bytes + spill_bytes
                      + (size_t)(N_NODES + 1) * sizeof(int);

    if (ws_size < need) {  // safety fallback: round-1 scatter path
        hipMemsetAsync(out, 0, (size_t)out_size * sizeof(float), stream);
        const long long total = (long long)N_EDGES * 16;
        scatter_add_kernel<<<(int)((total + 255) / 256), 256, 0, stream>>>(
            queue, weight, src, dst, out);
        return;
    }

    char* ws = (char*)d_ws;
    unsigned* csr = (unsigned*)ws;
    __half* qh    = (__half*)(ws + csr_bytes);
    uint2* spill  = (uint2*)(ws + csr_bytes + qh_bytes);
    int* cnt      = (int*)(ws + csr_bytes + qh_bytes + spill_bytes);
    int* spillcnt = cnt + N_NODES;

    hipMemsetAsync(cnt, 0, (size_t)(N_NODES + 1) * sizeof(int), stream);

    fill_kernel<<<FILL_BLOCKS, 256, 0, stream>>>(
        src, dst, weight, queue, cnt, csr, qh, spill, spillcnt);
    pull_kernel<<<PULL_BLOCKS, 256, 0, stream>>>(
        qh, queue, csr, cnt, spill, spillcnt, out);
}

// Round 3
// 141.759 us; speedup vs baseline: 1.1864x; 1.1864x over previous
//
#include <hip/hip_runtime.h>
#include <hip/hip_fp16.h>

#define N_NODES 50000
#define N_EDGES 800000
#define D_FEAT  64
#define CAP     32                      // slots/node: 128B = 2 lines; P(deg>32)~1e-5
#define SPILL_CAP 262144                // 2 MB; input is Poisson(16) -> ~0 used
#define FILL_BLOCKS 2048                // 8 partitions x 256 blocks
#define PART_MAGIC 687195ull            // ceil(2^32 / 6250); exact for dst < 2^16

// ---------------------------------------------------------------------------
// Round 12: fill = round-10 version (measured 45.6us, known good).
//   pull rebuilt around address-amortized gathers: 8 lanes x dwordx4 per
//   fp16 row, so ONE wave instruction gathers 8 edges (was 1 edge). Gather
//   instruction count drops 8x (TA address work 51M -> 6.4M addresses).
//   Entry list = one contiguous 128B load into lanes 0-31 + shfl per iter;
//   epilogue = shfl_xor reduce over the 8 edge-groups + two 16B stores.
// ---------------------------------------------------------------------------

typedef unsigned uvec4 __attribute__((ext_vector_type(4)));

__device__ __forceinline__ unsigned pack_entry(unsigned s, float w) {
    return (s << 16) | (unsigned)__half_as_ushort(__float2half(w));
}
__device__ __forceinline__ float entry_w(unsigned e) {
    return __half2float(__ushort_as_half((unsigned short)(e & 0xffffu)));
}
__device__ __forceinline__ int part_of(int d) {
    return (int)(((unsigned long long)(unsigned)d * PART_MAGIC) >> 32);
}
__device__ __forceinline__ float2 h2f2(unsigned u) {
    __half2 h = *reinterpret_cast<__half2*>(&u);
    return __half22float2(h);
}

__global__ void __launch_bounds__(256)
fill_kernel(const int* __restrict__ src, const int* __restrict__ dst,
            const float* __restrict__ weight, const float* __restrict__ queue,
            int* __restrict__ cnt, unsigned* __restrict__ csr,
            __half* __restrict__ qh, uint2* __restrict__ spill,
            int* __restrict__ spillcnt) {
    const int part = blockIdx.x & 7;              // XCD id (round-robin dispatch)
    const int bip  = blockIdx.x >> 3;
    const int nq   = N_EDGES / 4;                 // 200000 quads
    const int tstride = (FILL_BLOCKS / 8) * 256;  // 65536 threads/partition

    for (int t = bip * 256 + threadIdx.x; t < nq; t += tstride) {
        const int4 d4 = reinterpret_cast<const int4*>(dst)[t];
        const int p0 = part_of(d4.x), p1 = part_of(d4.y),
                  p2 = part_of(d4.z), p3 = part_of(d4.w);
        if (p0 != part && p1 != part && p2 != part && p3 != part) continue;
        const int4   s4 = reinterpret_cast<const int4*>(src)[t];
        const float4 w4 = reinterpret_cast<const float4*>(weight)[t];
        const int   pp[4] = {p0, p1, p2, p3};
        const int   ss[4] = {s4.x, s4.y, s4.z, s4.w};
        const int   dd[4] = {d4.x, d4.y, d4.z, d4.w};
        const float ww[4] = {w4.x, w4.y, w4.z, w4.w};
#pragma unroll
        for (int j = 0; j < 4; ++j) {
            if (pp[j] != part) continue;
            int pos = atomicAdd(&cnt[dd[j]], 1);
            if (pos < CAP) {
                csr[(size_t)dd[j] * CAP + pos] = pack_entry((unsigned)ss[j], ww[j]);
            } else {
                int sp = atomicAdd(spillcnt, 1);
                if (sp < SPILL_CAP)
                    spill[sp] = make_uint2((unsigned)ss[j] | ((unsigned)dd[j] << 16),
                                           __float_as_uint(ww[j]));
            }
        }
    }

    // Fused queue fp32 -> fp16 convert (coalesced float4 read, 8B write).
    const int gtid = blockIdx.x * 256 + threadIdx.x;      // 524288 threads
    for (int t = gtid; t < N_NODES * D_FEAT / 4; t += FILL_BLOCKS * 256) {
        const float4 q = reinterpret_cast<const float4*>(queue)[t];
        ushort4 h;
        h.x = __half_as_ushort(__float2half(q.x));
        h.y = __half_as_ushort(__float2half(q.y));
        h.z = __half_as_ushort(__float2half(q.z));
        h.w = __half_as_ushort(__float2half(q.w));
        reinterpret_cast<ushort4*>(qh)[t] = h;
    }
}

// One wave per node; 4 nodes per 256-thread block.
// Lane l: edge-group g = l>>3 (8 groups), chunk k = l&7 (16B of the 128B row).
// Group g handles slots {g, g+8, g+16, g+24}; one gather instr = 8 edges.
__global__ void __launch_bounds__(256)
pull_kernel(const __half* __restrict__ qh, const float* __restrict__ queue,
            const unsigned* __restrict__ csr, const int* __restrict__ cnt,
            const uint2* __restrict__ spill, const int* __restrict__ spillcnt,
            float* __restrict__ out) {
    const int node = blockIdx.x * 4 + (threadIdx.x >> 6);
    if (node >= N_NODES) return;                  // exact: 12500*4 = 50000
    const int lane = threadIdx.x & 63;
    const int g = lane >> 3;                      // edge group 0..7
    const int k = lane & 7;                       // 16B chunk within row

    const unsigned* p = csr + (size_t)node * CAP;
    const int c = min(cnt[node], CAP);            // wave-uniform
    const unsigned eown = p[lane & 31];           // whole entry list in-wave (128B)

    float a0 = 0, a1 = 0, a2 = 0, a3 = 0, a4 = 0, a5 = 0, a6 = 0, a7 = 0;

#pragma unroll
    for (int it = 0; it < 4; ++it) {
        if (it * 8 < c) {                         // wave-uniform tier skip
            const int slot = g + it * 8;          // 0..31
            unsigned e = __shfl(eown, slot);      // entry for this group's edge
            if (slot >= c) e = 0u;                // masked: src=0, w=fp16(0)
            const float w = entry_w(e);
            const uvec4 r = *reinterpret_cast<const uvec4*>(
                qh + (size_t)(e >> 16) * D_FEAT + k * 8);
            const float2 f0 = h2f2(r.x), f1 = h2f2(r.y),
                         f2 = h2f2(r.z), f3 = h2f2(r.w);
            a0 = fmaf(f0.x, w, a0);  a1 = fmaf(f0.y, w, a1);
            a2 = fmaf(f1.x, w, a2);  a3 = fmaf(f1.y, w, a3);
            a4 = fmaf(f2.x, w, a4);  a5 = fmaf(f2.y, w, a5);
            a6 = fmaf(f3.x, w, a6);  a7 = fmaf(f3.y, w, a7);
        }
    }

    // Cross-group reduce: groups differ in lane bits 3..5.
#pragma unroll
    for (int m = 8; m <= 32; m <<= 1) {
        a0 += __shfl_xor(a0, m);  a1 += __shfl_xor(a1, m);
        a2 += __shfl_xor(a2, m);  a3 += __shfl_xor(a3, m);
        a4 += __shfl_xor(a4, m);  a5 += __shfl_xor(a5, m);
        a6 += __shfl_xor(a6, m);  a7 += __shfl_xor(a7, m);
    }

    // Spill edges (normally zero). Lanes 0-7 hold final sums; add fp32 rows.
    const int nsp = min(*spillcnt, SPILL_CAP);
    if (nsp > 0 && lane < 8) {
        for (int t = 0; t < nsp; ++t) {
            const uint2 u = spill[t];
            if ((u.x >> 16) == (unsigned)node) {
                const float w = __uint_as_float(u.y);
                const float* qr = queue + (size_t)(u.x & 0xffffu) * D_FEAT + lane * 8;
                a0 = fmaf(qr[0], w, a0);  a1 = fmaf(qr[1], w, a1);
                a2 = fmaf(qr[2], w, a2);  a3 = fmaf(qr[3], w, a3);
                a4 = fmaf(qr[4], w, a4);  a5 = fmaf(qr[5], w, a5);
                a6 = fmaf(qr[6], w, a6);  a7 = fmaf(qr[7], w, a7);
            }
        }
    }

    if (lane < 8) {                               // 8 lanes x 32B = 256B row
        float* o = out + (size_t)node * D_FEAT + lane * 8;
        *reinterpret_cast<float4*>(o)     = make_float4(a0, a1, a2, a3);
        *reinterpret_cast<float4*>(o + 4) = make_float4(a4, a5, a6, a7);
    }
}

// --- Fallback (round-1 scatter) if ws_size is ever too small ---------------
__global__ void __launch_bounds__(256)
scatter_add_kernel(const float* __restrict__ queue,
                   const float* __restrict__ weight,
                   const int* __restrict__ src,
                   const int* __restrict__ dst,
                   float* __restrict__ out) {
    long long tid = (long long)blockIdx.x * blockDim.x + threadIdx.x;
    int e = (int)(tid >> 4);
    int c = ((int)tid & 15) << 2;
    if (e >= N_EDGES) return;
    int s = src[e], d = dst[e];
    float w = weight[e];
    const float4 q = *reinterpret_cast<const float4*>(queue + (size_t)s * D_FEAT + c);
    float* o = out + (size_t)d * D_FEAT + c;
    atomicAdd(o + 0, q.x * w);
    atomicAdd(o + 1, q.y * w);
    atomicAdd(o + 2, q.z * w);
    atomicAdd(o + 3, q.w * w);
}

extern "C" void kernel_launch(void* const* d_in, const int* in_sizes, int n_in,
                              void* d_out, int out_size, void* d_ws, size_t ws_size,
                              hipStream_t stream) {
    const float* queue  = (const float*)d_in[0];
    const float* weight = (const float*)d_in[1];
    const int*   src    = (const int*)d_in[2];
    const int*   dst    = (const int*)d_in[3];
    float* out = (float*)d_out;

    // Workspace layout (16B-aligned blocks):
    //   csr:      N_NODES*CAP unsigned   (6.4 MB)
    //   qh:       N_NODES*D_FEAT __half  (6.4 MB)
    //   spill:    SPILL_CAP uint2        (2 MB)
    //   cnt:      N_NODES int   \ zeroed together
    //   spillcnt: 1 int         /
    const size_t csr_bytes   = (size_t)N_NODES * CAP * sizeof(unsigned);
    const size_t qh_bytes    = (size_t)N_NODES * D_FEAT * sizeof(__half);
    const size_t spill_bytes = (size_t)SPILL_CAP * sizeof(uint2);
    const size_t need = csr_bytes + qh_bytes + spill_bytes
                      + (size_t)(N_NODES + 1) * sizeof(int);

    if (ws_size < need) {  // safety fallback: round-1 scatter path
        hipMemsetAsync(out, 0, (size_t)out_size * sizeof(float), stream);
        const long long total = (long long)N_EDGES * 16;
        scatter_add_kernel<<<(int)((total + 255) / 256), 256, 0, stream>>>(
            queue, weight, src, dst, out);
        return;
    }

    char* ws = (char*)d_ws;
    unsigned* csr = (unsigned*)ws;
    __half* qh    = (__half*)(ws + csr_bytes);
    uint2* spill  = (uint2*)(ws + csr_bytes + qh_bytes);
    int* cnt      = (int*)(ws + csr_bytes + qh_bytes + spill_bytes);
    int* spillcnt = cnt + N_NODES;

    hipMemsetAsync(cnt, 0, (size_t)(N_NODES + 1) * sizeof(int), stream);

    fill_kernel<<<FILL_BLOCKS, 256, 0, stream>>>(
        src, dst, weight, queue, cnt, csr, qh, spill, spillcnt);
    pull_kernel<<<(N_NODES + 3) / 4, 256, 0, stream>>>(
        qh, queue, csr, cnt, spill, spillcnt, out);
}